// Round 10
// baseline (2274.168 us; speedup 1.0000x reference)
//
#include <hip/hip_runtime.h>
#include <hip/hip_bf16.h>

typedef unsigned short u16;
typedef __attribute__((ext_vector_type(8))) short bf16x8;
typedef __attribute__((ext_vector_type(2))) short s16x2;
typedef __attribute__((ext_vector_type(4))) float f32x4;

#define N_NODES 50000
#define EDGES 500000
#define WPT 31250     // 16-edge groups per type
#define EPB 2048      // persistent edge blocks per type-launch
#define EPW (EPB * 4) // persistent edge waves per type-launch (8192)
#define NWAVES 3125   // node waves per type (50000/16)
#define NBLK 782      // ceil(NWAVES/4)

__device__ __forceinline__ u16 f2bf(float f) {
  return __builtin_bit_cast(u16, __float2bfloat16(f));
}
__device__ __forceinline__ float bf2f(u16 u) {
  return __builtin_bit_cast(float, ((unsigned)u) << 16);
}
__device__ __forceinline__ float bfe(bf16x8 v, int j) {
  return bf2f((u16)v[j]);
}

// packed bf16 atomic add (2 values at 4B-aligned address)
__device__ __forceinline__ void pk_atomic_bf16(u16* addr, float lo, float hi) {
#if __has_builtin(__builtin_amdgcn_global_atomic_fadd_v2bf16)
  s16x2 v;
  v[0] = (short)f2bf(lo);
  v[1] = (short)f2bf(hi);
  __builtin_amdgcn_global_atomic_fadd_v2bf16(
      (__attribute__((address_space(1))) s16x2*)addr, v);
#else
  unsigned* p = (unsigned*)addr;
  unsigned old = *p, assumed;
  do {
    assumed = old;
    float l2 = bf2f((u16)(assumed & 0xffff)) + lo;
    float h2 = bf2f((u16)(assumed >> 16)) + hi;
    unsigned nv = (unsigned)f2bf(l2) | ((unsigned)f2bf(h2) << 16);
    old = atomicCAS(p, assumed, nv);
  } while (old != assumed);
#endif
}

// ---------------------------------------------------------------------------
// Combined prep: weights -> bf16 tables (9 x 128x128), msgX zeroing, AND
// x fp32 -> bf16 cast (encoder2's GEMM chains moved into the edge kernel,
// so only the cast remains of it).
// blocks [0,576): weights; [576,6826): zero msgX; [6826,13076): cast x.
// ---------------------------------------------------------------------------
__global__ __launch_bounds__(256) void prep_all(
    const float* __restrict__ Wp, const float* __restrict__ Wc,
    const float* __restrict__ W1,
    const float* __restrict__ Wrel_ab, const float* __restrict__ Wroot_ab,
    const float* __restrict__ Wrel_ba, const float* __restrict__ Wroot_ba,
    const float* __restrict__ xa, const float* __restrict__ xb,
    u16* __restrict__ out, u16* __restrict__ msg,
    u16* __restrict__ xa_bf, u16* __restrict__ xb_bf)
{
  if (blockIdx.x >= 6826) {
    // cast 2 * 50000 * 128 fp32 -> bf16, 8 elems/thread, 6250 blocks
    int t = (blockIdx.x - 6826) * 256 + threadIdx.x;
    const int HALF = (N_NODES * 128) / 8;   // 800000
    const float* src;
    u16* dst;
    int idx;
    if (t < HALF) { src = xa; dst = xa_bf; idx = t * 8; }
    else          { src = xb; dst = xb_bf; idx = (t - HALF) * 8; }
    f32x4 a = *(const f32x4*)(src + idx);
    f32x4 b = *(const f32x4*)(src + idx + 4);
    bf16x8 o;
#pragma unroll
    for (int j = 0; j < 4; j++) {
      o[j]     = (short)f2bf(a[j]);
      o[j + 4] = (short)f2bf(b[j]);
    }
    *(bf16x8*)(dst + idx) = o;
    return;
  }
  if (blockIdx.x >= 576) {
    // zero 2 * N_NODES * 128 bf16, 8 per thread, 6250 blocks
    size_t t = (size_t)(blockIdx.x - 576) * 256 + threadIdx.x;
    bf16x8 z = {0, 0, 0, 0, 0, 0, 0, 0};
    *(bf16x8*)(msg + t * 8) = z;
    return;
  }
  int tid = blockIdx.x * 256 + threadIdx.x;  // 9*16384
  int m = tid >> 14;
  int idx = tid & 16383;
  int r = idx >> 7;
  int c = idx & 127;
  float val;
  switch (m) {
    case 0: val = Wp[r * 128 + c]; break;
    case 1: val = Wc[r * 128 + c]; break;
    case 2: val = W1[r * 384 + c]; break;
    case 3: val = W1[r * 384 + 128 + c]; break;
    case 4: val = W1[r * 384 + 256 + c]; break;
    case 5: val = Wrel_ab[r * 128 + c]; break;
    case 6: val = Wroot_ab[r * 128 + c]; break;
    case 7: val = Wrel_ba[r * 128 + c]; break;
    default: val = Wroot_ba[r * 128 + c]; break;
  }
  out[tid] = f2bf(val);
}

// ---------------------------------------------------------------------------
// out = msgX@Wrel^T + x@Wroot^T + brel + broot  (fp32 out), both types.
// ---------------------------------------------------------------------------
__global__ __launch_bounds__(256) void out_gemm2(
    const u16* __restrict__ xa_bf, const u16* __restrict__ xb_bf,
    const u16* __restrict__ msgX_a, const u16* __restrict__ msgX_b,
    const u16* __restrict__ Wrelba_b, const u16* __restrict__ Wrelab_b,
    const u16* __restrict__ Wrootba_b, const u16* __restrict__ Wrootab_b,
    const float* __restrict__ brel_ba, const float* __restrict__ broot_ba,
    const float* __restrict__ brel_ab, const float* __restrict__ broot_ab,
    float* __restrict__ out_a, float* __restrict__ out_b)
{
  int w = blockIdx.x * 4 + (threadIdx.x >> 6);
  int type = (w >= NBLK * 4) ? 1 : 0;
  int nw = w - type * NBLK * 4;
  if (nw >= NWAVES) return;
  const u16* xbf = type ? xb_bf : xa_bf;
  const u16* msg = type ? msgX_b : msgX_a;
  const u16* Wrel = type ? Wrelab_b : Wrelba_b;
  const u16* Wroot = type ? Wrootab_b : Wrootba_b;
  const float* brel = type ? brel_ab : brel_ba;
  const float* broot = type ? broot_ab : broot_ba;
  float* outp = type ? out_b : out_a;
  int row0 = nw * 16;
  int lane = threadIdx.x & 63;
  int col = lane & 15;
  int quad = lane >> 4;

  bf16x8 ax[4], am[4];
#pragma unroll
  for (int ks = 0; ks < 4; ks++) {
    ax[ks] = *(const bf16x8*)(xbf + (size_t)(row0 + col) * 128 + ks * 32 + quad * 8);
    am[ks] = *(const bf16x8*)(msg + (size_t)(row0 + col) * 128 + ks * 32 + quad * 8);
  }

  f32x4 zero = {0.f, 0.f, 0.f, 0.f};
  f32x4 acc[8];
#pragma unroll
  for (int nt = 0; nt < 8; nt++) acc[nt] = zero;
#pragma unroll
  for (int ks = 0; ks < 4; ks++) {
    const u16* wp1 = Wrel + col * 128 + ks * 32 + quad * 8;
    const u16* wp2 = Wroot + col * 128 + ks * 32 + quad * 8;
#pragma unroll
    for (int nt = 0; nt < 8; nt++) {
      bf16x8 b1f = *(const bf16x8*)(wp1 + nt * 2048);
      acc[nt] = __builtin_amdgcn_mfma_f32_16x16x32_bf16(am[ks], b1f, acc[nt], 0, 0, 0);
      bf16x8 b2f = *(const bf16x8*)(wp2 + nt * 2048);
      acc[nt] = __builtin_amdgcn_mfma_f32_16x16x32_bf16(ax[ks], b2f, acc[nt], 0, 0, 0);
    }
  }
#pragma unroll
  for (int nt = 0; nt < 8; nt++) {
    int c = nt * 16 + col;
    float b = brel[c] + broot[c];
#pragma unroll
    for (int r = 0; r < 4; r++)
      outp[(size_t)(row0 + quad * 4 + r) * 128 + c] = acc[nt][r] + b;
  }
}

// ---------------------------------------------------------------------------
// Persistent TYPE-COHERENT FULLY-FUSED edge kernel. The entire GraphEdgeWeight
// MLP runs in-kernel:
//   T = ep@W1a^T + ec@W1b^T + |xs-xd|@W1c^T + b1     (one fp32 accumulator;
//   ep = lrelu(xs@Wp^T+bp), ec = lrelu(xd@Wc^T+bc) computed on the fly from
//   the ALREADY-GATHERED af/d8 frags — u/v tables and their per-edge gathers
//   are deleted; redundant per-edge encoder compute is free at 3% MfmaUtil)
//   w = sigmoid(W2 . relu(T) + b2);  scatter w * xs into msgX (pk atomics).
// Register diet: af staged to a second per-wave LDS tile after its GEMM use;
// d8 dies after the ec chain; df after the W1c chain. No barriers (per-wave
// tiles, in-wave lgkmcnt ordering). No launch_bounds min (r5 spill lesson).
// ---------------------------------------------------------------------------
__global__ __launch_bounds__(256) void edge_fused_p(
    const u16* __restrict__ xs, const u16* __restrict__ xd,
    const int* __restrict__ ei,
    const u16* __restrict__ Wp_b, const float* __restrict__ bp,
    const u16* __restrict__ Wc_b, const float* __restrict__ bc,
    const u16* __restrict__ W1a, const u16* __restrict__ W1b,
    const u16* __restrict__ W1c, const float* __restrict__ b1,
    const float* __restrict__ W2, const float* __restrict__ b2p,
    u16* __restrict__ msgX)
{
  __shared__ u16 tld[4][2][2176];  // per wave: [0]=af tile, [1]=work tile
  int widx = threadIdx.x >> 6;
  int wt = blockIdx.x * 4 + widx;   // 0..EPW-1
  int lane = threadIdx.x & 63;
  int col = lane & 15;
  int quad = lane >> 4;
  int e4 = lane >> 2;
  int c0 = (lane & 3) * 32;
  u16* tA = tld[widx][0];
  u16* tT = tld[widx][1];
  float b2v = b2p[0];

  f32x4 zero = {0.f, 0.f, 0.f, 0.f};

  for (int g = wt; g < WPT; g += EPW) {
    int e0 = g * 16;
    int si = ei[e0 + col];
    int di = ei[EDGES + e0 + col];
    int d2 = ei[EDGES + e0 + e4];   // scatter dst (edge-major lane mapping)

    // x gathers — the ONLY per-edge global loads now
    bf16x8 af[4], d8[4];
#pragma unroll
    for (int ks = 0; ks < 4; ks++) {
      af[ks] = *(const bf16x8*)(xs + (size_t)si * 128 + ks * 32 + quad * 8);
      d8[ks] = *(const bf16x8*)(xd + (size_t)di * 128 + ks * 32 + quad * 8);
    }

    // df = |par - cld|
    bf16x8 df[4];
#pragma unroll
    for (int ks = 0; ks < 4; ks++)
#pragma unroll
      for (int j = 0; j < 8; j++)
        df[ks][j] = (short)f2bf(__builtin_fabsf(bfe(af[ks], j) - bfe(d8[ks], j)));

    f32x4 acc[8];
#pragma unroll
    for (int nt = 0; nt < 8; nt++) acc[nt] = zero;

    // ---- ep chain: lrelu(af@Wp^T+bp) -> tile -> acc += @W1a^T ----
    {
      f32x4 ea[8];
#pragma unroll
      for (int nt = 0; nt < 8; nt++) ea[nt] = zero;
#pragma unroll
      for (int ks = 0; ks < 4; ks++) {
        const u16* wp = Wp_b + col * 128 + ks * 32 + quad * 8;
#pragma unroll
        for (int nt = 0; nt < 8; nt++) {
          bf16x8 bf = *(const bf16x8*)(wp + nt * 2048);
          ea[nt] = __builtin_amdgcn_mfma_f32_16x16x32_bf16(af[ks], bf, ea[nt], 0, 0, 0);
        }
      }
#pragma unroll
      for (int nt = 0; nt < 8; nt++) {
        float be = bp[nt * 16 + col];
#pragma unroll
        for (int r = 0; r < 4; r++) {
          float v = ea[nt][r] + be;
          v = v > 0.f ? v : 0.01f * v;
          tT[(quad * 4 + r) * 136 + nt * 16 + col] = f2bf(v);
        }
      }
      bf16x8 a2[4];
#pragma unroll
      for (int ks = 0; ks < 4; ks++)
        a2[ks] = *(const bf16x8*)&tT[col * 136 + ks * 32 + quad * 8];
#pragma unroll
      for (int ks = 0; ks < 4; ks++) {
        const u16* wp = W1a + col * 128 + ks * 32 + quad * 8;
#pragma unroll
        for (int nt = 0; nt < 8; nt++) {
          bf16x8 bf = *(const bf16x8*)(wp + nt * 2048);
          acc[nt] = __builtin_amdgcn_mfma_f32_16x16x32_bf16(a2[ks], bf, acc[nt], 0, 0, 0);
        }
      }
    }

    // af no longer needed as MFMA operand: stage to af-tile for the scatter
#pragma unroll
    for (int ks = 0; ks < 4; ks++)
      *(bf16x8*)&tA[col * 136 + ks * 32 + quad * 8] = af[ks];

    // ---- ec chain: lrelu(d8@Wc^T+bc) -> tile -> acc += @W1b^T ----
    {
      f32x4 ea[8];
#pragma unroll
      for (int nt = 0; nt < 8; nt++) ea[nt] = zero;
#pragma unroll
      for (int ks = 0; ks < 4; ks++) {
        const u16* wp = Wc_b + col * 128 + ks * 32 + quad * 8;
#pragma unroll
        for (int nt = 0; nt < 8; nt++) {
          bf16x8 bf = *(const bf16x8*)(wp + nt * 2048);
          ea[nt] = __builtin_amdgcn_mfma_f32_16x16x32_bf16(d8[ks], bf, ea[nt], 0, 0, 0);
        }
      }
#pragma unroll
      for (int nt = 0; nt < 8; nt++) {
        float be = bc[nt * 16 + col];
#pragma unroll
        for (int r = 0; r < 4; r++) {
          float v = ea[nt][r] + be;
          v = v > 0.f ? v : 0.01f * v;
          tT[(quad * 4 + r) * 136 + nt * 16 + col] = f2bf(v);
        }
      }
      bf16x8 a2[4];
#pragma unroll
      for (int ks = 0; ks < 4; ks++)
        a2[ks] = *(const bf16x8*)&tT[col * 136 + ks * 32 + quad * 8];
#pragma unroll
      for (int ks = 0; ks < 4; ks++) {
        const u16* wp = W1b + col * 128 + ks * 32 + quad * 8;
#pragma unroll
        for (int nt = 0; nt < 8; nt++) {
          bf16x8 bf = *(const bf16x8*)(wp + nt * 2048);
          acc[nt] = __builtin_amdgcn_mfma_f32_16x16x32_bf16(a2[ks], bf, acc[nt], 0, 0, 0);
        }
      }
    }

    // ---- |d| chain: acc += df@W1c^T ----
#pragma unroll
    for (int ks = 0; ks < 4; ks++) {
      const u16* wp = W1c + col * 128 + ks * 32 + quad * 8;
#pragma unroll
      for (int nt = 0; nt < 8; nt++) {
        bf16x8 bf = *(const bf16x8*)(wp + nt * 2048);
        acc[nt] = __builtin_amdgcn_mfma_f32_16x16x32_bf16(df[ks], bf, acc[nt], 0, 0, 0);
      }
    }

    // T = acc + b1 -> tile (C-layout -> edge-major); single bf16 rounding
#pragma unroll
    for (int nt = 0; nt < 8; nt++) {
      float bb = b1[nt * 16 + col];
#pragma unroll
      for (int r = 0; r < 4; r++)
        tT[(quad * 4 + r) * 136 + nt * 16 + col] = f2bf(acc[nt][r] + bb);
    }

    // edge-major epilogue: w = sigmoid(W2 . relu(T) + b2)
    const u16* trow = &tT[e4 * 136 + c0];
    float p = 0.f;
#pragma unroll
    for (int k = 0; k < 4; k++) {
      bf16x8 tt = *(const bf16x8*)(trow + k * 8);
      f32x4 w0 = *(const f32x4*)(W2 + c0 + k * 8);
      f32x4 w1 = *(const f32x4*)(W2 + c0 + k * 8 + 4);
#pragma unroll
      for (int j = 0; j < 4; j++) {
        float q0 = bfe(tt, j);
        if (q0 > 0.f) p += q0 * w0[j];
        float q1 = bfe(tt, j + 4);
        if (q1 > 0.f) p += q1 * w1[j];
      }
    }
    p += __shfl_xor(p, 1, 64);
    p += __shfl_xor(p, 2, 64);
    float wgt = 1.f / (1.f + __expf(-(p + b2v)));

    // coalesced pk scatter from the af-tile (64B runs per dst row)
#pragma unroll
    for (int r = 0; r < 4; r++) {
      int src_lane = (quad * 4 + r) * 4;
      float wr = __shfl(wgt, src_lane, 64);
      int dr = __shfl(d2, src_lane, 64);
      u16* mrow = msgX + (size_t)dr * 128;
      const u16* xrow = &tA[(quad * 4 + r) * 136];
#pragma unroll
      for (int nt = 0; nt < 4; nt++) {
        int c = nt * 32 + col * 2;
        unsigned xv = *(const unsigned*)(xrow + c);
        pk_atomic_bf16(mrow + c, wr * bf2f((u16)(xv & 0xffff)),
                                 wr * bf2f((u16)(xv >> 16)));
      }
    }
  }
}

// ---------------------------------------------------------------------------
extern "C" void kernel_launch(void* const* d_in, const int* in_sizes, int n_in,
                              void* d_out, int out_size, void* d_ws, size_t ws_size,
                              hipStream_t stream) {
  const float* x_a      = (const float*)d_in[0];
  const float* x_b      = (const float*)d_in[1];
  const float* Wp       = (const float*)d_in[2];
  const float* bp       = (const float*)d_in[3];
  const float* Wc       = (const float*)d_in[4];
  const float* bc       = (const float*)d_in[5];
  const float* W1       = (const float*)d_in[6];
  const float* b1       = (const float*)d_in[7];
  const float* W2       = (const float*)d_in[8];
  const float* b2       = (const float*)d_in[9];
  const float* Wrel_ab  = (const float*)d_in[10];
  const float* brel_ab  = (const float*)d_in[11];
  const float* Wroot_ab = (const float*)d_in[12];
  const float* broot_ab = (const float*)d_in[13];
  const float* Wrel_ba  = (const float*)d_in[14];
  const float* brel_ba  = (const float*)d_in[15];
  const float* Wroot_ba = (const float*)d_in[16];
  const float* broot_ba = (const float*)d_in[17];
  const int*   ei_ab    = (const int*)d_in[18];
  const int*   ei_ba    = (const int*)d_in[19];

  char* ws = (char*)d_ws;
  u16* Wb        = (u16*)ws;               // 9*16384*2 B
  u16* Wp_b      = Wb + 0 * 16384;
  u16* Wc_b      = Wb + 1 * 16384;
  u16* W1a_b     = Wb + 2 * 16384;
  u16* W1b_b     = Wb + 3 * 16384;
  u16* W1c_b     = Wb + 4 * 16384;
  u16* Wrelab_b  = Wb + 5 * 16384;
  u16* Wrootab_b = Wb + 6 * 16384;
  u16* Wrelba_b  = Wb + 7 * 16384;
  u16* Wrootba_b = Wb + 8 * 16384;

  // bf16 node tables (u/v tables deleted — computed in-kernel now)
  u16* xa_bf   = (u16*)(ws + 1048576);
  u16* xb_bf   = (u16*)(ws + 13848576);
  u16* msgX_a  = (u16*)(ws + 26648576);    // contiguous pair, 25.6 MB total
  u16* msgX_b  = (u16*)(ws + 39448576);

  float* out_a = (float*)d_out;
  float* out_b = out_a + (size_t)N_NODES * 128;

  // 1. weights -> bf16 + msgX zeroing + x cast (576 + 6250 + 6250 blocks)
  prep_all<<<13076, 256, 0, stream>>>(Wp, Wc, W1, Wrel_ab, Wroot_ab,
                                      Wrel_ba, Wroot_ba, x_a, x_b,
                                      Wb, msgX_a, xa_bf, xb_bf);

  // 2a. edge phase, type A->B (par=x_a, cld=x_b, msg into msgX_b)
  edge_fused_p<<<EPB, 256, 0, stream>>>(xa_bf, xb_bf, ei_ab,
                                        Wp_b, bp, Wc_b, bc,
                                        W1a_b, W1b_b, W1c_b, b1,
                                        W2, b2, msgX_b);

  // 2b. edge phase, type B->A (par=x_b, cld=x_a, msg into msgX_a)
  edge_fused_p<<<EPB, 256, 0, stream>>>(xb_bf, xa_bf, ei_ba,
                                        Wp_b, bp, Wc_b, bc,
                                        W1a_b, W1b_b, W1c_b, b1,
                                        W2, b2, msgX_a);

  // 3. output GEMM
  out_gemm2<<<2 * NBLK, 256, 0, stream>>>(xa_bf, xb_bf, msgX_a, msgX_b,
                                          Wrelba_b, Wrelab_b,
                                          Wrootba_b, Wrootab_b,
                                          brel_ba, broot_ba, brel_ab, broot_ab,
                                          out_a, out_b);
}

// Round 11
// 2252.078 us; speedup vs baseline: 1.0098x; 1.0098x over previous
//
#include <hip/hip_runtime.h>
#include <hip/hip_bf16.h>

typedef unsigned short u16;
typedef __attribute__((ext_vector_type(8))) short bf16x8;
typedef __attribute__((ext_vector_type(2))) short s16x2;
typedef __attribute__((ext_vector_type(4))) float f32x4;

#define N_NODES 50000
#define EDGES 500000
#define WPT 31250     // 16-edge groups per type
#define EPB 2048      // persistent edge blocks per type-launch
#define EPW (EPB * 4) // persistent edge waves per type-launch (8192)
#define NWAVES 3125   // node waves per type (50000/16)
#define NBLK 782      // ceil(NWAVES/4)

__device__ __forceinline__ u16 f2bf(float f) {
  return __builtin_bit_cast(u16, __float2bfloat16(f));
}
__device__ __forceinline__ float bf2f(u16 u) {
  return __builtin_bit_cast(float, ((unsigned)u) << 16);
}
__device__ __forceinline__ float bfe(bf16x8 v, int j) {
  return bf2f((u16)v[j]);
}

// packed bf16 atomic add (2 values at 4B-aligned address)
__device__ __forceinline__ void pk_atomic_bf16(u16* addr, float lo, float hi) {
#if __has_builtin(__builtin_amdgcn_global_atomic_fadd_v2bf16)
  s16x2 v;
  v[0] = (short)f2bf(lo);
  v[1] = (short)f2bf(hi);
  __builtin_amdgcn_global_atomic_fadd_v2bf16(
      (__attribute__((address_space(1))) s16x2*)addr, v);
#else
  unsigned* p = (unsigned*)addr;
  unsigned old = *p, assumed;
  do {
    assumed = old;
    float l2 = bf2f((u16)(assumed & 0xffff)) + lo;
    float h2 = bf2f((u16)(assumed >> 16)) + hi;
    unsigned nv = (unsigned)f2bf(l2) | ((unsigned)f2bf(h2) << 16);
    old = atomicCAS(p, assumed, nv);
  } while (old != assumed);
#endif
}

// ---------------------------------------------------------------------------
// Combined prep: weights -> bf16 tables (9 x 128x128), msgX zeroing, AND
// x fp32 -> bf16 cast.
// blocks [0,576): weights; [576,6826): zero msgX; [6826,13076): cast x.
// ---------------------------------------------------------------------------
__global__ __launch_bounds__(256) void prep_all(
    const float* __restrict__ Wp, const float* __restrict__ Wc,
    const float* __restrict__ W1,
    const float* __restrict__ Wrel_ab, const float* __restrict__ Wroot_ab,
    const float* __restrict__ Wrel_ba, const float* __restrict__ Wroot_ba,
    const float* __restrict__ xa, const float* __restrict__ xb,
    u16* __restrict__ out, u16* __restrict__ msg,
    u16* __restrict__ xa_bf, u16* __restrict__ xb_bf)
{
  if (blockIdx.x >= 6826) {
    // cast 2 * 50000 * 128 fp32 -> bf16, 8 elems/thread, 6250 blocks
    int t = (blockIdx.x - 6826) * 256 + threadIdx.x;
    const int HALF = (N_NODES * 128) / 8;   // 800000
    const float* src;
    u16* dst;
    int idx;
    if (t < HALF) { src = xa; dst = xa_bf; idx = t * 8; }
    else          { src = xb; dst = xb_bf; idx = (t - HALF) * 8; }
    f32x4 a = *(const f32x4*)(src + idx);
    f32x4 b = *(const f32x4*)(src + idx + 4);
    bf16x8 o;
#pragma unroll
    for (int j = 0; j < 4; j++) {
      o[j]     = (short)f2bf(a[j]);
      o[j + 4] = (short)f2bf(b[j]);
    }
    *(bf16x8*)(dst + idx) = o;
    return;
  }
  if (blockIdx.x >= 576) {
    // zero 2 * N_NODES * 128 bf16, 8 per thread, 6250 blocks
    size_t t = (size_t)(blockIdx.x - 576) * 256 + threadIdx.x;
    bf16x8 z = {0, 0, 0, 0, 0, 0, 0, 0};
    *(bf16x8*)(msg + t * 8) = z;
    return;
  }
  int tid = blockIdx.x * 256 + threadIdx.x;  // 9*16384
  int m = tid >> 14;
  int idx = tid & 16383;
  int r = idx >> 7;
  int c = idx & 127;
  float val;
  switch (m) {
    case 0: val = Wp[r * 128 + c]; break;
    case 1: val = Wc[r * 128 + c]; break;
    case 2: val = W1[r * 384 + c]; break;
    case 3: val = W1[r * 384 + 128 + c]; break;
    case 4: val = W1[r * 384 + 256 + c]; break;
    case 5: val = Wrel_ab[r * 128 + c]; break;
    case 6: val = Wroot_ab[r * 128 + c]; break;
    case 7: val = Wrel_ba[r * 128 + c]; break;
    default: val = Wroot_ba[r * 128 + c]; break;
  }
  out[tid] = f2bf(val);
}

// ---------------------------------------------------------------------------
// out = msgX@Wrel^T + x@Wroot^T + brel + broot  (fp32 out), both types.
// ---------------------------------------------------------------------------
__global__ __launch_bounds__(256) void out_gemm2(
    const u16* __restrict__ xa_bf, const u16* __restrict__ xb_bf,
    const u16* __restrict__ msgX_a, const u16* __restrict__ msgX_b,
    const u16* __restrict__ Wrelba_b, const u16* __restrict__ Wrelab_b,
    const u16* __restrict__ Wrootba_b, const u16* __restrict__ Wrootab_b,
    const float* __restrict__ brel_ba, const float* __restrict__ broot_ba,
    const float* __restrict__ brel_ab, const float* __restrict__ broot_ab,
    float* __restrict__ out_a, float* __restrict__ out_b)
{
  int w = blockIdx.x * 4 + (threadIdx.x >> 6);
  int type = (w >= NBLK * 4) ? 1 : 0;
  int nw = w - type * NBLK * 4;
  if (nw >= NWAVES) return;
  const u16* xbf = type ? xb_bf : xa_bf;
  const u16* msg = type ? msgX_b : msgX_a;
  const u16* Wrel = type ? Wrelab_b : Wrelba_b;
  const u16* Wroot = type ? Wrootab_b : Wrootba_b;
  const float* brel = type ? brel_ab : brel_ba;
  const float* broot = type ? broot_ab : broot_ba;
  float* outp = type ? out_b : out_a;
  int row0 = nw * 16;
  int lane = threadIdx.x & 63;
  int col = lane & 15;
  int quad = lane >> 4;

  bf16x8 ax[4], am[4];
#pragma unroll
  for (int ks = 0; ks < 4; ks++) {
    ax[ks] = *(const bf16x8*)(xbf + (size_t)(row0 + col) * 128 + ks * 32 + quad * 8);
    am[ks] = *(const bf16x8*)(msg + (size_t)(row0 + col) * 128 + ks * 32 + quad * 8);
  }

  f32x4 zero = {0.f, 0.f, 0.f, 0.f};
  f32x4 acc[8];
#pragma unroll
  for (int nt = 0; nt < 8; nt++) acc[nt] = zero;
#pragma unroll
  for (int ks = 0; ks < 4; ks++) {
    const u16* wp1 = Wrel + col * 128 + ks * 32 + quad * 8;
    const u16* wp2 = Wroot + col * 128 + ks * 32 + quad * 8;
#pragma unroll
    for (int nt = 0; nt < 8; nt++) {
      bf16x8 b1f = *(const bf16x8*)(wp1 + nt * 2048);
      acc[nt] = __builtin_amdgcn_mfma_f32_16x16x32_bf16(am[ks], b1f, acc[nt], 0, 0, 0);
      bf16x8 b2f = *(const bf16x8*)(wp2 + nt * 2048);
      acc[nt] = __builtin_amdgcn_mfma_f32_16x16x32_bf16(ax[ks], b2f, acc[nt], 0, 0, 0);
    }
  }
#pragma unroll
  for (int nt = 0; nt < 8; nt++) {
    int c = nt * 16 + col;
    float b = brel[c] + broot[c];
#pragma unroll
    for (int r = 0; r < 4; r++)
      outp[(size_t)(row0 + quad * 4 + r) * 128 + c] = acc[nt][r] + b;
  }
}

// ---------------------------------------------------------------------------
// Persistent TYPE-COHERENT FULLY-FUSED edge kernel, register-disciplined v2.
// r10 spilled because acc[8] was live across both encoder chains. Fix:
// STRICT PHASE SEQUENCING — only ONE f32x4[8] accumulator live at any time:
//   ph1: ea = af@Wp   -> lrelu+bp -> ep-tile      (ea dies)
//        af -> tA tile                            (af dies)
//   ph2: ea = d8@Wc   -> lrelu+bc -> ec-tile      (ea, d8 die)
//   ph3: acc = ep@W1a + ec@W1b + df@W1c (from tiles; df dies)
//        T = acc+b1 -> ep-tile (overwrite)        (acc dies)
//   ph4: epilogue w = sigmoid(W2.relu(T)+b2); scatter w*af from tA.
// Peak live ~{af,d8,df,ea} = 80 regs + addressing. 3 LDS tiles/wave
// (52 KB/block -> 3 blocks/CU = 12 waves/CU, r4's good-traffic regime).
// No barriers (per-wave tiles, in-wave lgkmcnt ordering). No lb-min (r5).
// ---------------------------------------------------------------------------
__global__ __launch_bounds__(256) void edge_fused_p(
    const u16* __restrict__ xs, const u16* __restrict__ xd,
    const int* __restrict__ ei,
    const u16* __restrict__ Wp_b, const float* __restrict__ bp,
    const u16* __restrict__ Wc_b, const float* __restrict__ bc,
    const u16* __restrict__ W1a, const u16* __restrict__ W1b,
    const u16* __restrict__ W1c, const float* __restrict__ b1,
    const float* __restrict__ W2, const float* __restrict__ b2p,
    u16* __restrict__ msgX)
{
  __shared__ u16 tld[4][3][2176];  // per wave: [0]=af, [1]=ep/T, [2]=ec
  int widx = threadIdx.x >> 6;
  int wt = blockIdx.x * 4 + widx;   // 0..EPW-1
  int lane = threadIdx.x & 63;
  int col = lane & 15;
  int quad = lane >> 4;
  int e4 = lane >> 2;
  int c0 = (lane & 3) * 32;
  u16* tA  = tld[widx][0];
  u16* tEP = tld[widx][1];
  u16* tEC = tld[widx][2];
  float b2v = b2p[0];

  f32x4 zero = {0.f, 0.f, 0.f, 0.f};

  for (int g = wt; g < WPT; g += EPW) {
    int e0 = g * 16;
    int si = ei[e0 + col];
    int di = ei[EDGES + e0 + col];
    int d2 = ei[EDGES + e0 + e4];   // scatter dst (edge-major lane mapping)

    // x gathers — the ONLY per-edge global loads
    bf16x8 af[4], d8[4];
#pragma unroll
    for (int ks = 0; ks < 4; ks++) {
      af[ks] = *(const bf16x8*)(xs + (size_t)si * 128 + ks * 32 + quad * 8);
      d8[ks] = *(const bf16x8*)(xd + (size_t)di * 128 + ks * 32 + quad * 8);
    }

    // df = |par - cld|
    bf16x8 df[4];
#pragma unroll
    for (int ks = 0; ks < 4; ks++)
#pragma unroll
      for (int j = 0; j < 8; j++)
        df[ks][j] = (short)f2bf(__builtin_fabsf(bfe(af[ks], j) - bfe(d8[ks], j)));

    // ---- phase 1: ep = lrelu(af@Wp^T+bp) -> ep-tile; then af -> tA ----
    {
      f32x4 ea[8];
#pragma unroll
      for (int nt = 0; nt < 8; nt++) ea[nt] = zero;
#pragma unroll
      for (int ks = 0; ks < 4; ks++) {
        const u16* wp = Wp_b + col * 128 + ks * 32 + quad * 8;
#pragma unroll
        for (int nt = 0; nt < 8; nt++) {
          bf16x8 bf = *(const bf16x8*)(wp + nt * 2048);
          ea[nt] = __builtin_amdgcn_mfma_f32_16x16x32_bf16(af[ks], bf, ea[nt], 0, 0, 0);
        }
      }
#pragma unroll
      for (int nt = 0; nt < 8; nt++) {
        float be = bp[nt * 16 + col];
#pragma unroll
        for (int r = 0; r < 4; r++) {
          float v = ea[nt][r] + be;
          v = v > 0.f ? v : 0.01f * v;
          tEP[(quad * 4 + r) * 136 + nt * 16 + col] = f2bf(v);
        }
      }
    }
    // stage af for the scatter; af regs die here
#pragma unroll
    for (int ks = 0; ks < 4; ks++)
      *(bf16x8*)&tA[col * 136 + ks * 32 + quad * 8] = af[ks];

    // ---- phase 2: ec = lrelu(d8@Wc^T+bc) -> ec-tile; d8 dies ----
    {
      f32x4 ea[8];
#pragma unroll
      for (int nt = 0; nt < 8; nt++) ea[nt] = zero;
#pragma unroll
      for (int ks = 0; ks < 4; ks++) {
        const u16* wp = Wc_b + col * 128 + ks * 32 + quad * 8;
#pragma unroll
        for (int nt = 0; nt < 8; nt++) {
          bf16x8 bf = *(const bf16x8*)(wp + nt * 2048);
          ea[nt] = __builtin_amdgcn_mfma_f32_16x16x32_bf16(d8[ks], bf, ea[nt], 0, 0, 0);
        }
      }
#pragma unroll
      for (int nt = 0; nt < 8; nt++) {
        float be = bc[nt * 16 + col];
#pragma unroll
        for (int r = 0; r < 4; r++) {
          float v = ea[nt][r] + be;
          v = v > 0.f ? v : 0.01f * v;
          tEC[(quad * 4 + r) * 136 + nt * 16 + col] = f2bf(v);
        }
      }
    }

    // ---- phase 3: acc = ep@W1a + ec@W1b + df@W1c; T -> ep-tile ----
    {
      f32x4 acc[8];
#pragma unroll
      for (int nt = 0; nt < 8; nt++) acc[nt] = zero;

      bf16x8 a2[4];
#pragma unroll
      for (int ks = 0; ks < 4; ks++)
        a2[ks] = *(const bf16x8*)&tEP[col * 136 + ks * 32 + quad * 8];
#pragma unroll
      for (int ks = 0; ks < 4; ks++) {
        const u16* wp = W1a + col * 128 + ks * 32 + quad * 8;
#pragma unroll
        for (int nt = 0; nt < 8; nt++) {
          bf16x8 bf = *(const bf16x8*)(wp + nt * 2048);
          acc[nt] = __builtin_amdgcn_mfma_f32_16x16x32_bf16(a2[ks], bf, acc[nt], 0, 0, 0);
        }
      }
#pragma unroll
      for (int ks = 0; ks < 4; ks++)
        a2[ks] = *(const bf16x8*)&tEC[col * 136 + ks * 32 + quad * 8];
#pragma unroll
      for (int ks = 0; ks < 4; ks++) {
        const u16* wp = W1b + col * 128 + ks * 32 + quad * 8;
#pragma unroll
        for (int nt = 0; nt < 8; nt++) {
          bf16x8 bf = *(const bf16x8*)(wp + nt * 2048);
          acc[nt] = __builtin_amdgcn_mfma_f32_16x16x32_bf16(a2[ks], bf, acc[nt], 0, 0, 0);
        }
      }
#pragma unroll
      for (int ks = 0; ks < 4; ks++) {
        const u16* wp = W1c + col * 128 + ks * 32 + quad * 8;
#pragma unroll
        for (int nt = 0; nt < 8; nt++) {
          bf16x8 bf = *(const bf16x8*)(wp + nt * 2048);
          acc[nt] = __builtin_amdgcn_mfma_f32_16x16x32_bf16(df[ks], bf, acc[nt], 0, 0, 0);
        }
      }

      // T = acc + b1 -> ep-tile (overwrite; its a2 reads completed above)
#pragma unroll
      for (int nt = 0; nt < 8; nt++) {
        float bb = b1[nt * 16 + col];
#pragma unroll
        for (int r = 0; r < 4; r++)
          tEP[(quad * 4 + r) * 136 + nt * 16 + col] = f2bf(acc[nt][r] + bb);
      }
    }

    // ---- phase 4: w = sigmoid(W2 . relu(T) + b2), scatter from tA ----
    const u16* trow = &tEP[e4 * 136 + c0];
    float p = 0.f;
#pragma unroll
    for (int k = 0; k < 4; k++) {
      bf16x8 tt = *(const bf16x8*)(trow + k * 8);
      f32x4 w0 = *(const f32x4*)(W2 + c0 + k * 8);
      f32x4 w1 = *(const f32x4*)(W2 + c0 + k * 8 + 4);
#pragma unroll
      for (int j = 0; j < 4; j++) {
        float q0 = bfe(tt, j);
        if (q0 > 0.f) p += q0 * w0[j];
        float q1 = bfe(tt, j + 4);
        if (q1 > 0.f) p += q1 * w1[j];
      }
    }
    p += __shfl_xor(p, 1, 64);
    p += __shfl_xor(p, 2, 64);
    float wgt = 1.f / (1.f + __expf(-(p + b2v)));

    // coalesced pk scatter from the af-tile (64B runs per dst row)
#pragma unroll
    for (int r = 0; r < 4; r++) {
      int src_lane = (quad * 4 + r) * 4;
      float wr = __shfl(wgt, src_lane, 64);
      int dr = __shfl(d2, src_lane, 64);
      u16* mrow = msgX + (size_t)dr * 128;
      const u16* xrow = &tA[(quad * 4 + r) * 136];
#pragma unroll
      for (int nt = 0; nt < 4; nt++) {
        int c = nt * 32 + col * 2;
        unsigned xv = *(const unsigned*)(xrow + c);
        pk_atomic_bf16(mrow + c, wr * bf2f((u16)(xv & 0xffff)),
                                 wr * bf2f((u16)(xv >> 16)));
      }
    }
  }
}

// ---------------------------------------------------------------------------
extern "C" void kernel_launch(void* const* d_in, const int* in_sizes, int n_in,
                              void* d_out, int out_size, void* d_ws, size_t ws_size,
                              hipStream_t stream) {
  const float* x_a      = (const float*)d_in[0];
  const float* x_b      = (const float*)d_in[1];
  const float* Wp       = (const float*)d_in[2];
  const float* bp       = (const float*)d_in[3];
  const float* Wc       = (const float*)d_in[4];
  const float* bc       = (const float*)d_in[5];
  const float* W1       = (const float*)d_in[6];
  const float* b1       = (const float*)d_in[7];
  const float* W2       = (const float*)d_in[8];
  const float* b2       = (const float*)d_in[9];
  const float* Wrel_ab  = (const float*)d_in[10];
  const float* brel_ab  = (const float*)d_in[11];
  const float* Wroot_ab = (const float*)d_in[12];
  const float* broot_ab = (const float*)d_in[13];
  const float* Wrel_ba  = (const float*)d_in[14];
  const float* brel_ba  = (const float*)d_in[15];
  const float* Wroot_ba = (const float*)d_in[16];
  const float* broot_ba = (const float*)d_in[17];
  const int*   ei_ab    = (const int*)d_in[18];
  const int*   ei_ba    = (const int*)d_in[19];

  char* ws = (char*)d_ws;
  u16* Wb        = (u16*)ws;               // 9*16384*2 B
  u16* Wp_b      = Wb + 0 * 16384;
  u16* Wc_b      = Wb + 1 * 16384;
  u16* W1a_b     = Wb + 2 * 16384;
  u16* W1b_b     = Wb + 3 * 16384;
  u16* W1c_b     = Wb + 4 * 16384;
  u16* Wrelab_b  = Wb + 5 * 16384;
  u16* Wrootab_b = Wb + 6 * 16384;
  u16* Wrelba_b  = Wb + 7 * 16384;
  u16* Wrootba_b = Wb + 8 * 16384;

  // bf16 node tables (u/v tables deleted — computed in-kernel now)
  u16* xa_bf   = (u16*)(ws + 1048576);
  u16* xb_bf   = (u16*)(ws + 13848576);
  u16* msgX_a  = (u16*)(ws + 26648576);    // contiguous pair, 25.6 MB total
  u16* msgX_b  = (u16*)(ws + 39448576);

  float* out_a = (float*)d_out;
  float* out_b = out_a + (size_t)N_NODES * 128;

  // 1. weights -> bf16 + msgX zeroing + x cast (576 + 6250 + 6250 blocks)
  prep_all<<<13076, 256, 0, stream>>>(Wp, Wc, W1, Wrel_ab, Wroot_ab,
                                      Wrel_ba, Wroot_ba, x_a, x_b,
                                      Wb, msgX_a, xa_bf, xb_bf);

  // 2a. edge phase, type A->B (par=x_a, cld=x_b, msg into msgX_b)
  edge_fused_p<<<EPB, 256, 0, stream>>>(xa_bf, xb_bf, ei_ab,
                                        Wp_b, bp, Wc_b, bc,
                                        W1a_b, W1b_b, W1c_b, b1,
                                        W2, b2, msgX_b);

  // 2b. edge phase, type B->A (par=x_b, cld=x_a, msg into msgX_a)
  edge_fused_p<<<EPB, 256, 0, stream>>>(xb_bf, xa_bf, ei_ba,
                                        Wp_b, bp, Wc_b, bc,
                                        W1a_b, W1b_b, W1c_b, b1,
                                        W2, b2, msgX_a);

  // 3. output GEMM
  out_gemm2<<<2 * NBLK, 256, 0, stream>>>(xa_bf, xb_bf, msgX_a, msgX_b,
                                          Wrelba_b, Wrelab_b,
                                          Wrootba_b, Wrootab_b,
                                          brel_ba, broot_ba, brel_ab, broot_ab,
                                          out_a, out_b);
}

// Round 12
// 640.506 us; speedup vs baseline: 3.5506x; 3.5161x over previous
//
#include <hip/hip_runtime.h>
#include <hip/hip_bf16.h>

typedef unsigned short u16;
typedef __attribute__((ext_vector_type(8))) short bf16x8;
typedef __attribute__((ext_vector_type(2))) short s16x2;
typedef __attribute__((ext_vector_type(4))) float f32x4;

#define N_NODES 50000
#define EDGES 500000
#define WPT 31250     // 16-edge groups per type
#define EPB 2048      // persistent edge blocks per type-launch
#define EPW (EPB * 4) // persistent edge waves per type-launch (8192)
#define NWAVES 3125   // node waves per type (50000/16)
#define NBLK 782      // ceil(NWAVES/4)

__device__ __forceinline__ u16 f2bf(float f) {
  return __builtin_bit_cast(u16, __float2bfloat16(f));
}
__device__ __forceinline__ float bf2f(u16 u) {
  return __builtin_bit_cast(float, ((unsigned)u) << 16);
}
__device__ __forceinline__ float bfe(bf16x8 v, int j) {
  return bf2f((u16)v[j]);
}

// packed bf16 atomic add (2 values at 4B-aligned address)
__device__ __forceinline__ void pk_atomic_bf16(u16* addr, float lo, float hi) {
#if __has_builtin(__builtin_amdgcn_global_atomic_fadd_v2bf16)
  s16x2 v;
  v[0] = (short)f2bf(lo);
  v[1] = (short)f2bf(hi);
  __builtin_amdgcn_global_atomic_fadd_v2bf16(
      (__attribute__((address_space(1))) s16x2*)addr, v);
#else
  unsigned* p = (unsigned*)addr;
  unsigned old = *p, assumed;
  do {
    assumed = old;
    float l2 = bf2f((u16)(assumed & 0xffff)) + lo;
    float h2 = bf2f((u16)(assumed >> 16)) + hi;
    unsigned nv = (unsigned)f2bf(l2) | ((unsigned)f2bf(h2) << 16);
    old = atomicCAS(p, assumed, nv);
  } while (old != assumed);
#endif
}

// ---------------------------------------------------------------------------
// weights -> bf16 tables (9 x 128x128 row-major), PLUS msgX zeroing
// 0 Wp, 1 Wc, 2 W1a, 3 W1b, 4 W1c, 5 Wrel_ab, 6 Wroot_ab, 7 Wrel_ba, 8 Wroot_ba
// ---------------------------------------------------------------------------
__global__ __launch_bounds__(256) void prep_weights_zero(
    const float* __restrict__ Wp, const float* __restrict__ Wc,
    const float* __restrict__ W1,
    const float* __restrict__ Wrel_ab, const float* __restrict__ Wroot_ab,
    const float* __restrict__ Wrel_ba, const float* __restrict__ Wroot_ba,
    u16* __restrict__ out, u16* __restrict__ msg)
{
  if (blockIdx.x >= 576) {
    // zero 2 * N_NODES * 128 bf16 = 12.8M u16, 8 per thread, 6250 blocks
    size_t t = (size_t)(blockIdx.x - 576) * 256 + threadIdx.x;
    bf16x8 z = {0, 0, 0, 0, 0, 0, 0, 0};
    *(bf16x8*)(msg + t * 8) = z;
    return;
  }
  int tid = blockIdx.x * 256 + threadIdx.x;  // 9*16384
  int m = tid >> 14;
  int idx = tid & 16383;
  int r = idx >> 7;
  int c = idx & 127;
  float val;
  switch (m) {
    case 0: val = Wp[r * 128 + c]; break;
    case 1: val = Wc[r * 128 + c]; break;
    case 2: val = W1[r * 384 + c]; break;
    case 3: val = W1[r * 384 + 128 + c]; break;
    case 4: val = W1[r * 384 + 256 + c]; break;
    case 5: val = Wrel_ab[r * 128 + c]; break;
    case 6: val = Wroot_ab[r * 128 + c]; break;
    case 7: val = Wrel_ba[r * 128 + c]; break;
    default: val = Wroot_ba[r * 128 + c]; break;
  }
  out[tid] = f2bf(val);
}

// ---------------------------------------------------------------------------
// Fused encoder + x cast, both node sets in one dispatch (grid 2*NBLK):
//   u = lrelu(x@Wp^T+bp) @ W1a^T + b1   (b1 folded in)
//   v = lrelu(x@Wc^T+bc) @ W1b^T
// ---------------------------------------------------------------------------
__global__ __launch_bounds__(256) void encoder2(
    const float* __restrict__ xa, const float* __restrict__ xb,
    const u16* __restrict__ Wp_b, const float* __restrict__ bp,
    const u16* __restrict__ Wc_b, const float* __restrict__ bc,
    const u16* __restrict__ W1a_b, const float* __restrict__ b1,
    const u16* __restrict__ W1b_b,
    u16* __restrict__ xa_bf, u16* __restrict__ xb_bf,
    u16* __restrict__ u_a, u16* __restrict__ v_a,
    u16* __restrict__ u_b, u16* __restrict__ v_b)
{
  __shared__ u16 tile[4][2176];   // 16 x pitch 136 bf16, per wave
  int widx = threadIdx.x >> 6;
  int w = blockIdx.x * 4 + widx;         // 0 .. 2*4*NBLK-1
  int type = (w >= NBLK * 4) ? 1 : 0;
  int nw = w - type * NBLK * 4;
  if (nw >= NWAVES) nw = NWAVES - 1;     // clamp (dup work; per-wave tile, safe)
  const float* x = type ? xb : xa;
  u16* xbf_out = type ? xb_bf : xa_bf;
  u16* u_out = type ? u_b : u_a;
  u16* v_out = type ? v_b : v_a;
  int row0 = nw * 16;
  int lane = threadIdx.x & 63;
  int col = lane & 15;
  int quad = lane >> 4;
  u16* tl = tile[widx];

  bf16x8 af[4];
#pragma unroll
  for (int ks = 0; ks < 4; ks++) {
    const float* xp = x + (size_t)(row0 + col) * 128 + ks * 32 + quad * 8;
    f32x4 lo = *(const f32x4*)xp;
    f32x4 hi = *(const f32x4*)(xp + 4);
    bf16x8 o;
#pragma unroll
    for (int j = 0; j < 4; j++) {
      o[j]     = (short)f2bf(lo[j]);
      o[j + 4] = (short)f2bf(hi[j]);
    }
    af[ks] = o;
    *(bf16x8*)(xbf_out + (size_t)(row0 + col) * 128 + ks * 32 + quad * 8) = o;
  }

  f32x4 zero = {0.f, 0.f, 0.f, 0.f};

  for (int chain = 0; chain < 2; chain++) {
    const u16* Wenc = chain ? Wc_b : Wp_b;
    const float* benc = chain ? bc : bp;
    const u16* Wmix = chain ? W1b_b : W1a_b;
    const float* bmix = chain ? nullptr : b1;
    u16* outp = chain ? v_out : u_out;

    f32x4 acc[8];
#pragma unroll
    for (int nt = 0; nt < 8; nt++) acc[nt] = zero;
#pragma unroll
    for (int ks = 0; ks < 4; ks++) {
      const u16* wp = Wenc + col * 128 + ks * 32 + quad * 8;
#pragma unroll
      for (int nt = 0; nt < 8; nt++) {
        bf16x8 bf = *(const bf16x8*)(wp + nt * 2048);
        acc[nt] = __builtin_amdgcn_mfma_f32_16x16x32_bf16(af[ks], bf, acc[nt], 0, 0, 0);
      }
    }
    // per-wave tile: in-wave lgkmcnt ordering suffices, no barrier
#pragma unroll
    for (int nt = 0; nt < 8; nt++) {
      float be = benc[nt * 16 + col];
#pragma unroll
      for (int r = 0; r < 4; r++) {
        float v = acc[nt][r] + be;
        v = v > 0.f ? v : 0.01f * v;
        tl[(quad * 4 + r) * 136 + nt * 16 + col] = f2bf(v);
      }
    }
    bf16x8 a2[4];
#pragma unroll
    for (int ks = 0; ks < 4; ks++)
      a2[ks] = *(const bf16x8*)&tl[col * 136 + ks * 32 + quad * 8];

    f32x4 acc2[8];
#pragma unroll
    for (int nt = 0; nt < 8; nt++) acc2[nt] = zero;
#pragma unroll
    for (int ks = 0; ks < 4; ks++) {
      const u16* wp = Wmix + col * 128 + ks * 32 + quad * 8;
#pragma unroll
      for (int nt = 0; nt < 8; nt++) {
        bf16x8 bf = *(const bf16x8*)(wp + nt * 2048);
        acc2[nt] = __builtin_amdgcn_mfma_f32_16x16x32_bf16(a2[ks], bf, acc2[nt], 0, 0, 0);
      }
    }
#pragma unroll
    for (int nt = 0; nt < 8; nt++) {
      float bm = bmix ? bmix[nt * 16 + col] : 0.f;
#pragma unroll
      for (int r = 0; r < 4; r++)
        outp[(size_t)(row0 + quad * 4 + r) * 128 + nt * 16 + col] = f2bf(acc2[nt][r] + bm);
    }
  }
}

// ---------------------------------------------------------------------------
// out = msgX@Wrel^T + x@Wroot^T + brel + broot  (fp32 out), both types.
// ---------------------------------------------------------------------------
__global__ __launch_bounds__(256) void out_gemm2(
    const u16* __restrict__ xa_bf, const u16* __restrict__ xb_bf,
    const u16* __restrict__ msgX_a, const u16* __restrict__ msgX_b,
    const u16* __restrict__ Wrelba_b, const u16* __restrict__ Wrelab_b,
    const u16* __restrict__ Wrootba_b, const u16* __restrict__ Wrootab_b,
    const float* __restrict__ brel_ba, const float* __restrict__ broot_ba,
    const float* __restrict__ brel_ab, const float* __restrict__ broot_ab,
    float* __restrict__ out_a, float* __restrict__ out_b)
{
  int w = blockIdx.x * 4 + (threadIdx.x >> 6);
  int type = (w >= NBLK * 4) ? 1 : 0;
  int nw = w - type * NBLK * 4;
  if (nw >= NWAVES) return;
  const u16* xbf = type ? xb_bf : xa_bf;
  const u16* msg = type ? msgX_b : msgX_a;
  const u16* Wrel = type ? Wrelab_b : Wrelba_b;
  const u16* Wroot = type ? Wrootab_b : Wrootba_b;
  const float* brel = type ? brel_ab : brel_ba;
  const float* broot = type ? broot_ab : broot_ba;
  float* outp = type ? out_b : out_a;
  int row0 = nw * 16;
  int lane = threadIdx.x & 63;
  int col = lane & 15;
  int quad = lane >> 4;

  bf16x8 ax[4], am[4];
#pragma unroll
  for (int ks = 0; ks < 4; ks++) {
    ax[ks] = *(const bf16x8*)(xbf + (size_t)(row0 + col) * 128 + ks * 32 + quad * 8);
    am[ks] = *(const bf16x8*)(msg + (size_t)(row0 + col) * 128 + ks * 32 + quad * 8);
  }

  f32x4 zero = {0.f, 0.f, 0.f, 0.f};
  f32x4 acc[8];
#pragma unroll
  for (int nt = 0; nt < 8; nt++) acc[nt] = zero;
#pragma unroll
  for (int ks = 0; ks < 4; ks++) {
    const u16* wp1 = Wrel + col * 128 + ks * 32 + quad * 8;
    const u16* wp2 = Wroot + col * 128 + ks * 32 + quad * 8;
#pragma unroll
    for (int nt = 0; nt < 8; nt++) {
      bf16x8 b1f = *(const bf16x8*)(wp1 + nt * 2048);
      acc[nt] = __builtin_amdgcn_mfma_f32_16x16x32_bf16(am[ks], b1f, acc[nt], 0, 0, 0);
      bf16x8 b2f = *(const bf16x8*)(wp2 + nt * 2048);
      acc[nt] = __builtin_amdgcn_mfma_f32_16x16x32_bf16(ax[ks], b2f, acc[nt], 0, 0, 0);
    }
  }
#pragma unroll
  for (int nt = 0; nt < 8; nt++) {
    int c = nt * 16 + col;
    float b = brel[c] + broot[c];
#pragma unroll
    for (int r = 0; r < 4; r++)
      outp[(size_t)(row0 + quad * 4 + r) * 128 + c] = acc[nt][r] + b;
  }
}

// ---------------------------------------------------------------------------
// Persistent TYPE-COHERENT fused edge kernel (round-4 configuration — the
// session's measured optimum). One type per launch: instantaneous working
// set = one type's 4 node tables + 1 msgX (clean 0.37 GB/launch traffic);
// ~3.6 waves/CU keeps L2 reuse intact (higher occupancy raises traffic
// faster than bandwidth — measured r6). Plain loop, no prefetch (r9: ILP
// pipeline is exactly neutral here).
// ---------------------------------------------------------------------------
__global__ __launch_bounds__(256) void edge_fused_p(
    const u16* __restrict__ xs, const u16* __restrict__ xd,
    const int* __restrict__ ei,
    const u16* __restrict__ W1c,
    const u16* __restrict__ uT, const u16* __restrict__ vT,
    const float* __restrict__ W2, const float* __restrict__ b2p,
    u16* __restrict__ msgX)
{
  __shared__ u16 tld[4][2176];   // 16 x pitch 136 bf16, per wave (17.4 KB)
  int widx = threadIdx.x >> 6;
  int wt = blockIdx.x * 4 + widx;   // 0..EPW-1
  int lane = threadIdx.x & 63;
  int col = lane & 15;
  int quad = lane >> 4;
  int e4 = lane >> 2;
  int c0 = (lane & 3) * 32;
  u16* tl = tld[widx];
  float b2v = b2p[0];

  for (int g = wt; g < WPT; g += EPW) {
    int e0 = g * 16;

    int si = ei[e0 + col];
    int di = ei[EDGES + e0 + col];
    int s2 = ei[e0 + e4];
    int d2 = ei[EDGES + e0 + e4];

    // x gathers (col-layout) — feed the MFMA chain; af kept for the scatter
    bf16x8 af[4], d8[4];
#pragma unroll
    for (int ks = 0; ks < 4; ks++) {
      af[ks] = *(const bf16x8*)(xs + (size_t)si * 128 + ks * 32 + quad * 8);
      d8[ks] = *(const bf16x8*)(xd + (size_t)di * 128 + ks * 32 + quad * 8);
    }

    // df = |par - cld|  (d8 dies here)
    bf16x8 df[4];
#pragma unroll
    for (int ks = 0; ks < 4; ks++)
#pragma unroll
      for (int j = 0; j < 8; j++)
        df[ks][j] = (short)f2bf(__builtin_fabsf(bfe(af[ks], j) - bfe(d8[ks], j)));

    // 32 MFMAs (t = d @ W1c^T)
    f32x4 zero = {0.f, 0.f, 0.f, 0.f};
    f32x4 acc[8];
#pragma unroll
    for (int nt = 0; nt < 8; nt++) acc[nt] = zero;
#pragma unroll
    for (int ks = 0; ks < 4; ks++) {
      const u16* wp = W1c + col * 128 + ks * 32 + quad * 8;
#pragma unroll
      for (int nt = 0; nt < 8; nt++) {
        bf16x8 bf = *(const bf16x8*)(wp + nt * 2048);
        acc[nt] = __builtin_amdgcn_mfma_f32_16x16x32_bf16(df[ks], bf, acc[nt], 0, 0, 0);
      }
    }

    // u/v gathers (edge-major) — TLP covers the latency
    const u16* urow = uT + (size_t)s2 * 128 + c0;
    const u16* vrow = vT + (size_t)d2 * 128 + c0;
    bf16x8 UU[4], VV[4];
#pragma unroll
    for (int k = 0; k < 4; k++) {
      UU[k] = *(const bf16x8*)(urow + k * 8);
      VV[k] = *(const bf16x8*)(vrow + k * 8);
    }

    // t -> tile (C-layout -> edge-major); acc dies here
#pragma unroll
    for (int nt = 0; nt < 8; nt++)
#pragma unroll
      for (int r = 0; r < 4; r++)
        tl[(quad * 4 + r) * 136 + nt * 16 + col] = f2bf(acc[nt][r]);

    // edge-major epilogue: w = sigmoid(W2 . relu(t + u + v) + b2)
    const u16* trow = &tl[e4 * 136 + c0];
    float p = 0.f;
#pragma unroll
    for (int k = 0; k < 4; k++) {
      bf16x8 tt = *(const bf16x8*)(trow + k * 8);
      f32x4 w0 = *(const f32x4*)(W2 + c0 + k * 8);
      f32x4 w1 = *(const f32x4*)(W2 + c0 + k * 8 + 4);
#pragma unroll
      for (int j = 0; j < 4; j++) {
        float q0 = bfe(tt, j) + bfe(UU[k], j) + bfe(VV[k], j);
        if (q0 > 0.f) p += q0 * w0[j];
        float q1 = bfe(tt, j + 4) + bfe(UU[k], j + 4) + bfe(VV[k], j + 4);
        if (q1 > 0.f) p += q1 * w1[j];
      }
    }
    p += __shfl_xor(p, 1, 64);
    p += __shfl_xor(p, 2, 64);
    float wgt = 1.f / (1.f + __expf(-(p + b2v)));

    // af -> same per-wave tile (t reads above are in-wave ordered),
    // then coalesced pk scatter (64B runs per dst row)
#pragma unroll
    for (int ks = 0; ks < 4; ks++)
      *(bf16x8*)&tl[col * 136 + ks * 32 + quad * 8] = af[ks];
#pragma unroll
    for (int r = 0; r < 4; r++) {
      int src_lane = (quad * 4 + r) * 4;
      float wr = __shfl(wgt, src_lane, 64);
      int dr = __shfl(d2, src_lane, 64);
      u16* mrow = msgX + (size_t)dr * 128;
      const u16* xrow = &tl[(quad * 4 + r) * 136];
#pragma unroll
      for (int nt = 0; nt < 4; nt++) {
        int c = nt * 32 + col * 2;
        unsigned xv = *(const unsigned*)(xrow + c);
        pk_atomic_bf16(mrow + c, wr * bf2f((u16)(xv & 0xffff)),
                                 wr * bf2f((u16)(xv >> 16)));
      }
    }
  }
}

// ---------------------------------------------------------------------------
extern "C" void kernel_launch(void* const* d_in, const int* in_sizes, int n_in,
                              void* d_out, int out_size, void* d_ws, size_t ws_size,
                              hipStream_t stream) {
  const float* x_a      = (const float*)d_in[0];
  const float* x_b      = (const float*)d_in[1];
  const float* Wp       = (const float*)d_in[2];
  const float* bp       = (const float*)d_in[3];
  const float* Wc       = (const float*)d_in[4];
  const float* bc       = (const float*)d_in[5];
  const float* W1       = (const float*)d_in[6];
  const float* b1       = (const float*)d_in[7];
  const float* W2       = (const float*)d_in[8];
  const float* b2       = (const float*)d_in[9];
  const float* Wrel_ab  = (const float*)d_in[10];
  const float* brel_ab  = (const float*)d_in[11];
  const float* Wroot_ab = (const float*)d_in[12];
  const float* broot_ab = (const float*)d_in[13];
  const float* Wrel_ba  = (const float*)d_in[14];
  const float* brel_ba  = (const float*)d_in[15];
  const float* Wroot_ba = (const float*)d_in[16];
  const float* broot_ba = (const float*)d_in[17];
  const int*   ei_ab    = (const int*)d_in[18];
  const int*   ei_ba    = (const int*)d_in[19];

  char* ws = (char*)d_ws;
  u16* Wb        = (u16*)ws;               // 9*16384*2 B
  u16* Wp_b      = Wb + 0 * 16384;
  u16* Wc_b      = Wb + 1 * 16384;
  u16* W1a_b     = Wb + 2 * 16384;
  u16* W1b_b     = Wb + 3 * 16384;
  u16* W1c_b     = Wb + 4 * 16384;
  u16* Wrelab_b  = Wb + 5 * 16384;
  u16* Wrootab_b = Wb + 6 * 16384;
  u16* Wrelba_b  = Wb + 7 * 16384;
  u16* Wrootba_b = Wb + 8 * 16384;

  // 12.8 MB bf16 node tables
  u16* xa_bf   = (u16*)(ws + 1048576);
  u16* xb_bf   = (u16*)(ws + 13848576);
  u16* u_a     = (u16*)(ws + 26648576);
  u16* v_a     = (u16*)(ws + 39448576);
  u16* u_b     = (u16*)(ws + 52248576);
  u16* v_b     = (u16*)(ws + 65048576);
  u16* msgX_a  = (u16*)(ws + 77848576);    // contiguous pair, 25.6 MB total
  u16* msgX_b  = (u16*)(ws + 90648576);

  float* out_a = (float*)d_out;
  float* out_b = out_a + (size_t)N_NODES * 128;

  // 1. weights -> bf16 + msgX zeroing (576 weight blocks + 6250 zero blocks)
  prep_weights_zero<<<6826, 256, 0, stream>>>(Wp, Wc, W1, Wrel_ab, Wroot_ab,
                                              Wrel_ba, Wroot_ba, Wb, msgX_a);

  // 2. encoder + x fp32->bf16 cast fused
  encoder2<<<2 * NBLK, 256, 0, stream>>>(x_a, x_b, Wp_b, bp, Wc_b, bc,
                                         W1a_b, b1, W1b_b,
                                         xa_bf, xb_bf, u_a, v_a, u_b, v_b);

  // 3a. edge phase, type A->B (src=x_a, dst in B, msg into msgX_b)
  edge_fused_p<<<EPB, 256, 0, stream>>>(xa_bf, xb_bf, ei_ab, W1c_b,
                                        u_a, v_b, W2, b2, msgX_b);

  // 3b. edge phase, type B->A (src=x_b, dst in A, msg into msgX_a)
  edge_fused_p<<<EPB, 256, 0, stream>>>(xb_bf, xa_bf, ei_ba, W1c_b,
                                        u_b, v_a, W2, b2, msgX_a);

  // 4. output GEMM
  out_gemm2<<<2 * NBLK, 256, 0, stream>>>(xa_bf, xb_bf, msgX_a, msgX_b,
                                          Wrelba_b, Wrelab_b,
                                          Wrootba_b, Wrootab_b,
                                          brel_ba, broot_ba, brel_ab, broot_ab,
                                          out_a, out_b);
}